// Round 9
// baseline (319.911 us; speedup 1.0000x reference)
//
#include <hip/hip_runtime.h>

typedef __bf16 bf16_t;
typedef __bf16 bf16x8 __attribute__((ext_vector_type(8)));
typedef float f32x4 __attribute__((ext_vector_type(4)));
typedef unsigned short u16;

// ---------- helpers ----------
__device__ __forceinline__ u16 f2bf(float f) {
  unsigned u = __float_as_uint(f);
  unsigned r = (u + 0x7fffu + ((u >> 16) & 1u)) >> 16;
  return (u16)r;
}
__device__ __forceinline__ float bf2f(u16 u) {
  return __uint_as_float(((unsigned)u) << 16);
}

typedef const unsigned __attribute__((address_space(1)))* gptr_t;
typedef unsigned __attribute__((address_space(3)))* lptr_t;

__device__ __forceinline__ void gload_lds16(const u16* g, u16* l) {
  __builtin_amdgcn_global_load_lds((gptr_t)(const void*)g, (lptr_t)(void*)l, 16, 0, 0);
}

#define QSCALE 0.18033688f  // 0.125 * log2(e): folds 1/sqrt(64) and exp->exp2
#define EPS 136             // epilogue LDS row stride (u16): 272B, 16B-aligned rows

// ---------- fp32 -> bf16 convert (inputs) ----------
__global__ __launch_bounds__(256) void cvt_f32_bf16(const float* __restrict__ in,
                                                    u16* __restrict__ out, int n4) {
  int i = blockIdx.x * 256 + threadIdx.x;
  if (i >= n4) return;
  float4 v = reinterpret_cast<const float4*>(in)[i];
  ushort4 o;
  o.x = f2bf(v.x); o.y = f2bf(v.y); o.z = f2bf(v.z); o.w = f2bf(v.w);
  reinterpret_cast<ushort4*>(out)[i] = o;
}

// ---------- all 4 weights fp32 -> bf16 in one dispatch ----------
__global__ __launch_bounds__(256) void cvt_w4(const float* __restrict__ Wq,
                                              const float* __restrict__ Wk,
                                              const float* __restrict__ Wv,
                                              const float* __restrict__ Wo,
                                              u16* __restrict__ out) {
  int sel = blockIdx.y;
  const float* in = sel == 0 ? Wq : sel == 1 ? Wk : sel == 2 ? Wv : Wo;
  u16* o = out + sel * 589824;
  int i = blockIdx.x * 256 + threadIdx.x;  // < 147456
  float4 v = reinterpret_cast<const float4*>(in)[i];
  ushort4 ov;
  ov.x = f2bf(v.x); ov.y = f2bf(v.y); ov.z = f2bf(v.z); ov.w = f2bf(v.w);
  reinterpret_cast<ushort4*>(o)[i] = ov;
}

// ---------- adj bit-pack:  [8,1024,1024] int32 -> [8,1024,32] u32 ----------
__global__ __launch_bounds__(256) void pack_adj(const int* __restrict__ adj,
                                                unsigned* __restrict__ bits) {
  unsigned idx = blockIdx.x * 256u + threadIdx.x;   // < 8388608
  int a = adj[idx];
  unsigned long long m = __ballot(a != 0);
  int l = threadIdx.x & 63;
  if ((l & 31) == 0) bits[idx >> 5] = (unsigned)(m >> (l & 32));
}

// ---------- fused QKV GEMM: A[8192,768] x {Wq,Wk,Wv}[768,768]^T + bias ----------
// blockIdx.y in [0,18): 0-5 -> Q (scaled, [b,h,s,d]), 6-11 -> K ([b,h,s,d]),
// 12-17 -> V (transposed [b,h,d,s]).  Epilogue: LDS roundtrip -> dwordx4 stores.
__global__ __launch_bounds__(256) void gemm_qkv(
    const u16* __restrict__ A,
    const u16* __restrict__ Wq, const u16* __restrict__ Wk, const u16* __restrict__ Wv,
    const float* __restrict__ bq, const float* __restrict__ bk, const float* __restrict__ bv,
    u16* __restrict__ Qo, u16* __restrict__ Ko, u16* __restrict__ Vo) {
  __shared__ u16 lds[2][2][128 * 32];   // 32 KB staging; reused by epilogue
  const int tid = threadIdx.x;
  const int w = tid >> 6, l = tid & 63;
  const int bm = blockIdx.x;
  const int bn = blockIdx.y;
  const int sel = bn / 6;          // 0=Q 1=K 2=V (wave-uniform)
  const int bnl = bn % 6;
  const int lr = l & 15, lg = l >> 4;
  const int wm = w >> 1, wn = w & 1;

  const u16* W = sel == 0 ? Wq : sel == 1 ? Wk : Wv;
  const float* bias = sel == 0 ? bq : sel == 1 ? bk : bv;

  const u16* Abase = A + (bm * 128) * 768;
  const u16* Wbase = W + (bnl * 128) * 768;

  f32x4 acc[4][4];
#pragma unroll
  for (int i = 0; i < 4; ++i)
#pragma unroll
    for (int j = 0; j < 4; ++j) acc[i][j] = f32x4{0.f, 0.f, 0.f, 0.f};

  auto stage = [&](int buf, int k0) {
#pragma unroll
    for (int r = 0; r < 2; ++r) {
      int rowoff = r * 64 + w * 16;                       // wave-uniform
      const u16* ga = Abase + (rowoff + (l >> 2)) * 768 + k0 + (l & 3) * 8;
      const u16* gw = Wbase + (rowoff + (l >> 2)) * 768 + k0 + (l & 3) * 8;
      gload_lds16(ga, &lds[buf][0][rowoff * 32]);
      gload_lds16(gw, &lds[buf][1][rowoff * 32]);
    }
  };

  stage(0, 0);
  int cur = 0;
  for (int kt = 0; kt < 24; ++kt) {
    __syncthreads();
    if (kt < 23) stage(cur ^ 1, (kt + 1) * 32);
    const u16* la = &lds[cur][0][0];
    const u16* lb = &lds[cur][1][0];
    bf16x8 af[4], bw[4];
#pragma unroll
    for (int i = 0; i < 4; ++i)
      af[i] = *(const bf16x8*)&la[(wm * 64 + i * 16 + lr) * 32 + lg * 8];
#pragma unroll
    for (int j = 0; j < 4; ++j)
      bw[j] = *(const bf16x8*)&lb[(wn * 64 + j * 16 + lr) * 32 + lg * 8];
#pragma unroll
    for (int i = 0; i < 4; ++i)
#pragma unroll
      for (int j = 0; j < 4; ++j)
        acc[i][j] = __builtin_amdgcn_mfma_f32_16x16x32_bf16(af[i], bw[j], acc[i][j], 0, 0, 0);
    cur ^= 1;
  }

  __syncthreads();                       // all LDS reads done -> safe to reuse as ep
  u16* ep = &lds[0][0][0];               // 64 x EPS tile (17.4 KB)
  const int n0 = bnl * 128 + wn * 64;

  if (sel != 2) {
    // Q/K: [b,h,s,d]; LDS tile [m_local][n], b16 writes, b128 reads, dwordx4 stores
    const float sc = sel == 0 ? QSCALE : 1.0f;
    u16* dst = sel == 0 ? Qo : Ko;
#pragma unroll
    for (int p = 0; p < 2; ++p) {
      if (wm == p) {
#pragma unroll
        for (int j = 0; j < 4; ++j) {
          float bs = bias[n0 + j * 16 + lr];
#pragma unroll
          for (int i = 0; i < 4; ++i)
#pragma unroll
            for (int r = 0; r < 4; ++r)
              ep[(i * 16 + lg * 4 + r) * EPS + wn * 64 + j * 16 + lr] =
                  f2bf((acc[i][j][r] + bs) * sc);
        }
      }
      __syncthreads();
#pragma unroll
      for (int it = 0; it < 4; ++it) {
        int u = it * 256 + tid, row = u >> 4, cc = u & 15;
        uint4 val = *(const uint4*)&ep[row * EPS + cc * 8];
        int m = bm * 128 + p * 64 + row;
        int b_ = m >> 10, s_ = m & 1023;
        int h_ = (bnl * 128 + cc * 8) >> 6, d_ = (cc & 7) * 8;
        *(uint4*)&dst[((b_ * 12 + h_) * 1024 + s_) * 64 + d_] = val;
      }
      __syncthreads();
    }
  } else {
    // V: [b,h,d,s]; LDS tile transposed [n_local][m], b64 writes
#pragma unroll
    for (int p = 0; p < 2; ++p) {
      if (wn == p) {
#pragma unroll
        for (int j = 0; j < 4; ++j) {
          float bs = bias[n0 + j * 16 + lr];
#pragma unroll
          for (int i = 0; i < 4; ++i) {
            ushort4 o4;
            o4.x = f2bf(acc[i][j][0] + bs);
            o4.y = f2bf(acc[i][j][1] + bs);
            o4.z = f2bf(acc[i][j][2] + bs);
            o4.w = f2bf(acc[i][j][3] + bs);
            *(ushort4*)&ep[(j * 16 + lr) * EPS + wm * 64 + i * 16 + lg * 4] = o4;
          }
        }
      }
      __syncthreads();
#pragma unroll
      for (int it = 0; it < 4; ++it) {
        int u = it * 256 + tid, row = u >> 4, cc = u & 15;
        uint4 val = *(const uint4*)&ep[row * EPS + cc * 8];
        int dg = bnl * 128 + p * 64 + row;
        int h_ = dg >> 6, d_ = dg & 63;
        int b_ = bm >> 3, s_ = (bm & 7) * 128 + cc * 8;
        *(uint4*)&Vo[((b_ * 12 + h_) * 64 + d_) * 1024 + s_] = val;
      }
      __syncthreads();
    }
  }
}

// ---------- O-proj GEMM: bf16 out[m][768] = acc + bias (resid folded into LN) ----------
__global__ __launch_bounds__(256) void gemm_o(
    const u16* __restrict__ A, const u16* __restrict__ W,
    const float* __restrict__ bias, u16* __restrict__ xb) {
  __shared__ u16 lds[2][2][128 * 32];
  const int tid = threadIdx.x;
  const int w = tid >> 6, l = tid & 63;
  const int bm = blockIdx.x, bn = blockIdx.y;
  const int lr = l & 15, lg = l >> 4;
  const int wm = w >> 1, wn = w & 1;

  const u16* Abase = A + (bm * 128) * 768;
  const u16* Wbase = W + (bn * 128) * 768;

  f32x4 acc[4][4];
#pragma unroll
  for (int i = 0; i < 4; ++i)
#pragma unroll
    for (int j = 0; j < 4; ++j) acc[i][j] = f32x4{0.f, 0.f, 0.f, 0.f};

  auto stage = [&](int buf, int k0) {
#pragma unroll
    for (int r = 0; r < 2; ++r) {
      int rowoff = r * 64 + w * 16;
      const u16* ga = Abase + (rowoff + (l >> 2)) * 768 + k0 + (l & 3) * 8;
      const u16* gw = Wbase + (rowoff + (l >> 2)) * 768 + k0 + (l & 3) * 8;
      gload_lds16(ga, &lds[buf][0][rowoff * 32]);
      gload_lds16(gw, &lds[buf][1][rowoff * 32]);
    }
  };

  stage(0, 0);
  int cur = 0;
  for (int kt = 0; kt < 24; ++kt) {
    __syncthreads();
    if (kt < 23) stage(cur ^ 1, (kt + 1) * 32);
    const u16* la = &lds[cur][0][0];
    const u16* lb = &lds[cur][1][0];
    bf16x8 af[4], bw[4];
#pragma unroll
    for (int i = 0; i < 4; ++i)
      af[i] = *(const bf16x8*)&la[(wm * 64 + i * 16 + lr) * 32 + lg * 8];
#pragma unroll
    for (int j = 0; j < 4; ++j)
      bw[j] = *(const bf16x8*)&lb[(wn * 64 + j * 16 + lr) * 32 + lg * 8];
#pragma unroll
    for (int i = 0; i < 4; ++i)
#pragma unroll
      for (int j = 0; j < 4; ++j)
        acc[i][j] = __builtin_amdgcn_mfma_f32_16x16x32_bf16(af[i], bw[j], acc[i][j], 0, 0, 0);
    cur ^= 1;
  }

  __syncthreads();
  u16* ep = &lds[0][0][0];
  const int n0 = bn * 128 + wn * 64;
#pragma unroll
  for (int p = 0; p < 2; ++p) {
    if (wm == p) {
#pragma unroll
      for (int j = 0; j < 4; ++j) {
        float bs = bias[n0 + j * 16 + lr];
#pragma unroll
        for (int i = 0; i < 4; ++i)
#pragma unroll
          for (int r = 0; r < 4; ++r)
            ep[(i * 16 + lg * 4 + r) * EPS + wn * 64 + j * 16 + lr] =
                f2bf(acc[i][j][r] + bs);
      }
    }
    __syncthreads();
#pragma unroll
    for (int it = 0; it < 4; ++it) {
      int u = it * 256 + tid, row = u >> 4, cc = u & 15;
      uint4 val = *(const uint4*)&ep[row * EPS + cc * 8];
      int m = bm * 128 + p * 64 + row;
      *(uint4*)&xb[m * 768 + bn * 128 + cc * 8] = val;
    }
    __syncthreads();
  }
}

// ---------- attention v4: K in LDS (dbuf), V direct from L2, higher occupancy ----------
// grid (96,16): bh = blockIdx.x -> XCD = bh%8 (per-head K/V pinned to one XCD L2).
// LDS 24KB -> 6 blocks/CU; launch_bounds(256,4) caps VGPR at 128.
__global__ __launch_bounds__(256, 4) void attn(
    const u16* __restrict__ Q,   // [96,1024,64]
    const u16* __restrict__ Kt,  // [96,1024,64]
    const u16* __restrict__ VT,  // [96,64,1024]
    const unsigned* __restrict__ bits, // [8,1024,32]
    u16* __restrict__ ctx) {     // [8,1024,768]
  __shared__ u16 kl[2][64 * 64];        // 16 KB (K dbuf)
  __shared__ u16 plds_all[4][16 * 64];  // 8 KB
  const int tid = threadIdx.x;
  const int w = tid >> 6, l = tid & 63;
  const int lr = l & 15, lg = l >> 4;
  const int bh = blockIdx.x;               // 0..95
  const int qt = (blockIdx.y << 2) | w;    // 0..63
  const int b_ = bh / 12, h_ = bh % 12;
  u16* plds = plds_all[w];

  const u16* Qb = Q + (bh * 1024 + qt * 16) * 64;
  const u16* Kb = Kt + bh * 1024 * 64;
  const u16* Vb = VT + bh * 64 * 1024;
  const unsigned* wb = bits + (b_ * 1024 + qt * 16) * 32;

  bf16x8 qa0 = *(const bf16x8*)&Qb[lr * 64 + lg * 8];
  bf16x8 qa1 = *(const bf16x8*)&Qb[lr * 64 + 32 + lg * 8];

  bf16x8 vones;
#pragma unroll
  for (int i = 0; i < 8; ++i) vones[i] = (__bf16)1.0f;

  f32x4 cacc[4];
#pragma unroll
  for (int j = 0; j < 4; ++j) cacc[j] = f32x4{0.f, 0.f, 0.f, 0.f};
  f32x4 lacc = f32x4{0.f, 0.f, 0.f, 0.f};

  // cooperative K-tile stage (8 KB): granule-XOR pre-swizzled on the GLOBAL addr
  auto stage = [&](int buf, int k0) {
#pragma unroll
    for (int j2 = 0; j2 < 2; ++j2) {
      const int c = j2 * 256 + tid;         // chunk 0..511
      const int row = c >> 3, g = c & 7;
      const int gp = ((g ^ (row & 7)) << 3);
      gload_lds16(Kb + (k0 + row) * 64 + gp, &kl[buf][c * 8]);
    }
  };

  stage(0, 0);
  __syncthreads();
  int cur = 0;

  for (int kt = 0; kt < 16; ++kt) {
    const int k0 = kt * 64;
    if (kt < 15) stage(cur ^ 1, k0 + 64);   // next-tile DMA first

    uint2 mm[4];
#pragma unroll
    for (int r = 0; r < 4; ++r)
      mm[r] = *(const uint2*)&wb[(lg * 4 + r) * 32 + kt * 2];

    // QK^T from LDS K-tile (swizzled reads, conflict-free)
    f32x4 s[4];
#pragma unroll
    for (int t = 0; t < 4; ++t) {
      const int row = t * 16 + lr;
      const int sw = row & 7;
      bf16x8 ka = *(const bf16x8*)&kl[cur][row * 64 + ((lg ^ sw) << 3)];
      bf16x8 kb2 = *(const bf16x8*)&kl[cur][row * 64 + (((4 + lg) ^ sw) << 3)];
      f32x4 z = f32x4{0.f, 0.f, 0.f, 0.f};
      z = __builtin_amdgcn_mfma_f32_16x16x32_bf16(qa0, ka, z, 0, 0, 0);
      z = __builtin_amdgcn_mfma_f32_16x16x32_bf16(qa1, kb2, z, 0, 0, 0);
      s[t] = z;
    }

    // V direct from global (L2-resident, XCD-local); issue before exp/P roundtrip
    const u16* vp0 = &Vb[(0 * 16 + lr) * 1024 + k0 + lg * 8];
    const u16* vp1 = &Vb[(1 * 16 + lr) * 1024 + k0 + lg * 8];
    const u16* vp2 = &Vb[(2 * 16 + lr) * 1024 + k0 + lg * 8];
    const u16* vp3 = &Vb[(3 * 16 + lr) * 1024 + k0 + lg * 8];
    bf16x8 vv0 = *(const bf16x8*)vp0;
    bf16x8 vv1 = *(const bf16x8*)(vp0 + 32);
    bf16x8 vv2 = *(const bf16x8*)vp1;
    bf16x8 vv3 = *(const bf16x8*)(vp1 + 32);
    bf16x8 vv4 = *(const bf16x8*)vp2;
    bf16x8 vv5 = *(const bf16x8*)(vp2 + 32);
    bf16x8 vv6 = *(const bf16x8*)vp3;
    bf16x8 vv7 = *(const bf16x8*)(vp3 + 32);

    // mask + exp2 + bf16 + swizzled P-LDS write (conflict-free)
#pragma unroll
    for (int r = 0; r < 4; ++r) {
      const int q = lg * 4 + r;
      const int sw = (q & 7) << 3;
      unsigned w0 = mm[r].x >> lr;
      unsigned w1 = mm[r].y >> lr;
#pragma unroll
      for (int t = 0; t < 4; ++t) {
        unsigned bit = (t == 0) ? (w0 & 1u)
                     : (t == 1) ? ((w0 >> 16) & 1u)
                     : (t == 2) ? (w1 & 1u)
                                : ((w1 >> 16) & 1u);
        float sv = bit ? s[t][r] : -1e30f;
        float p = exp2f(sv);
        plds[q * 64 + ((t * 16 + lr) ^ sw)] = f2bf(p);
      }
    }
    asm volatile("s_waitcnt lgkmcnt(0)" ::: "memory");
    const int swr = (lr & 7) << 3;
    bf16x8 pa0 = *(const bf16x8*)&plds[lr * 64 + ((lg * 8) ^ swr)];
    bf16x8 pa1 = *(const bf16x8*)&plds[lr * 64 + ((32 + lg * 8) ^ swr)];

    __builtin_amdgcn_s_setprio(1);
    lacc = __builtin_amdgcn_mfma_f32_16x16x32_bf16(pa0, vones, lacc, 0, 0, 0);
    lacc = __builtin_amdgcn_mfma_f32_16x16x32_bf16(pa1, vones, lacc, 0, 0, 0);
    cacc[0] = __builtin_amdgcn_mfma_f32_16x16x32_bf16(pa0, vv0, cacc[0], 0, 0, 0);
    cacc[0] = __builtin_amdgcn_mfma_f32_16x16x32_bf16(pa1, vv1, cacc[0], 0, 0, 0);
    cacc[1] = __builtin_amdgcn_mfma_f32_16x16x32_bf16(pa0, vv2, cacc[1], 0, 0, 0);
    cacc[1] = __builtin_amdgcn_mfma_f32_16x16x32_bf16(pa1, vv3, cacc[1], 0, 0, 0);
    cacc[2] = __builtin_amdgcn_mfma_f32_16x16x32_bf16(pa0, vv4, cacc[2], 0, 0, 0);
    cacc[2] = __builtin_amdgcn_mfma_f32_16x16x32_bf16(pa1, vv5, cacc[2], 0, 0, 0);
    cacc[3] = __builtin_amdgcn_mfma_f32_16x16x32_bf16(pa0, vv6, cacc[3], 0, 0, 0);
    cacc[3] = __builtin_amdgcn_mfma_f32_16x16x32_bf16(pa1, vv7, cacc[3], 0, 0, 0);
    __builtin_amdgcn_s_setprio(0);

    __syncthreads();   // drains K-DMA (vmcnt) + P reads; next tile resident
    cur ^= 1;
  }

  float inv[4];
#pragma unroll
  for (int r = 0; r < 4; ++r) inv[r] = 1.0f / lacc[r];
#pragma unroll
  for (int j = 0; j < 4; ++j) {
#pragma unroll
    for (int r = 0; r < 4; ++r) {
      int q = qt * 16 + lg * 4 + r;
      ctx[(b_ * 1024 + q) * 768 + h_ * 64 + j * 16 + lr] = f2bf(cacc[j][r] * inv[r]);
    }
  }
}

// ---------- LayerNorm (+ residual add): x = bf16(gemm_o out) + fp32 inputs ----------
__global__ __launch_bounds__(256) void layernorm(const u16* __restrict__ xb,
                                                 const float* __restrict__ resid,
                                                 const float* __restrict__ gamma,
                                                 const float* __restrict__ beta,
                                                 float* __restrict__ out) {
  int row = blockIdx.x * 4 + (threadIdx.x >> 6);
  int l = threadIdx.x & 63;
  const ushort4* xr = (const ushort4*)(xb + row * 768);
  const float4* rr = (const float4*)(resid + row * 768);
  float v[12];
  float s = 0.f;
#pragma unroll
  for (int c = 0; c < 3; ++c) {
    ushort4 xs = xr[l + c * 64];
    float4 rv = rr[l + c * 64];
    v[c * 4 + 0] = bf2f(xs.x) + rv.x;
    v[c * 4 + 1] = bf2f(xs.y) + rv.y;
    v[c * 4 + 2] = bf2f(xs.z) + rv.z;
    v[c * 4 + 3] = bf2f(xs.w) + rv.w;
    s += v[c * 4 + 0] + v[c * 4 + 1] + v[c * 4 + 2] + v[c * 4 + 3];
  }
#pragma unroll
  for (int d = 1; d < 64; d <<= 1) s += __shfl_xor(s, d);
  float mu = s * (1.0f / 768.0f);
  float vs = 0.f;
#pragma unroll
  for (int k = 0; k < 12; ++k) {
    float q = v[k] - mu;
    vs += q * q;
  }
#pragma unroll
  for (int d = 1; d < 64; d <<= 1) vs += __shfl_xor(vs, d);
  float rs = rsqrtf(vs * (1.0f / 768.0f) + 1e-5f);
  const float4* g4 = (const float4*)gamma;
  const float4* b4 = (const float4*)beta;
#pragma unroll
  for (int c = 0; c < 3; ++c) {
    float4 g = g4[l + c * 64], bb = b4[l + c * 64];
    float4 o;
    o.x = (v[c * 4 + 0] - mu) * rs * g.x + bb.x;
    o.y = (v[c * 4 + 1] - mu) * rs * g.y + bb.y;
    o.z = (v[c * 4 + 2] - mu) * rs * g.z + bb.z;
    o.w = (v[c * 4 + 3] - mu) * rs * g.w + bb.w;
    ((float4*)(out + row * 768))[l + c * 64] = o;
  }
}

// ---------- launch ----------
extern "C" void kernel_launch(void* const* d_in, const int* in_sizes, int n_in,
                              void* d_out, int out_size, void* d_ws, size_t ws_size,
                              hipStream_t stream) {
  (void)in_sizes; (void)n_in; (void)out_size; (void)ws_size;
  const float* inputs = (const float*)d_in[0];
  const int* adj = (const int*)d_in[1];
  const float* Wq = (const float*)d_in[2];
  const float* bq = (const float*)d_in[3];
  const float* Wk = (const float*)d_in[4];
  const float* bk = (const float*)d_in[5];
  const float* Wv = (const float*)d_in[6];
  const float* bv = (const float*)d_in[7];
  const float* Wo = (const float*)d_in[8];
  const float* bo = (const float*)d_in[9];
  const float* gamma = (const float*)d_in[10];
  const float* beta = (const float*)d_in[11];
  float* out = (float*)d_out;
  char* ws = (char*)d_ws;

  // workspace layout (bytes)
  u16* Xbf = (u16*)(ws + 0);              // 12,582,912  (ctx bf16 aliases this later)
  u16* Wqb = (u16*)(ws + 12582912);       //  4 x 1,179,648 contiguous (cvt_w4)
  u16* Wkb = (u16*)(ws + 13762560);
  u16* Wvb = (u16*)(ws + 14942208);
  u16* Wob = (u16*)(ws + 16121856);
  u16* Qb  = (u16*)(ws + 17301504);       // 12,582,912  (xb bf16 aliases this later)
  u16* Kb  = (u16*)(ws + 29884416);       // 12,582,912
  u16* VTb = (u16*)(ws + 42467328);       // 12,582,912
  unsigned* bits = (unsigned*)(ws + 55050240); // 1,048,576  -> total 56,098,816
  u16* ctxb = (u16*)(ws + 0);
  u16* xb = (u16*)(ws + 17301504);

  cvt_f32_bf16<<<6144, 256, 0, stream>>>(inputs, Xbf, 1572864);
  cvt_w4<<<dim3(576, 4), 256, 0, stream>>>(Wq, Wk, Wv, Wo, Wqb);
  pack_adj<<<32768, 256, 0, stream>>>(adj, bits);

  gemm_qkv<<<dim3(64, 18), 256, 0, stream>>>(Xbf, Wqb, Wkb, Wvb, bq, bk, bv, Qb, Kb, VTb);

  attn<<<dim3(96, 16), 256, 0, stream>>>(Qb, Kb, VTb, bits, ctxb);

  gemm_o<<<dim3(64, 6), 256, 0, stream>>>(ctxb, Wob, bo, xb);

  layernorm<<<2048, 256, 0, stream>>>(xb, inputs, gamma, beta, out);
}

// Round 10
// 255.102 us; speedup vs baseline: 1.2541x; 1.2541x over previous
//
#include <hip/hip_runtime.h>

typedef __bf16 bf16_t;
typedef __bf16 bf16x8 __attribute__((ext_vector_type(8)));
typedef float f32x4 __attribute__((ext_vector_type(4)));
typedef unsigned short u16;

// ---------- helpers ----------
__device__ __forceinline__ u16 f2bf(float f) {
  unsigned u = __float_as_uint(f);
  unsigned r = (u + 0x7fffu + ((u >> 16) & 1u)) >> 16;
  return (u16)r;
}
__device__ __forceinline__ float bf2f(u16 u) {
  return __uint_as_float(((unsigned)u) << 16);
}

typedef const unsigned __attribute__((address_space(1)))* gptr_t;
typedef unsigned __attribute__((address_space(3)))* lptr_t;

__device__ __forceinline__ void gload_lds16(const u16* g, u16* l) {
  __builtin_amdgcn_global_load_lds((gptr_t)(const void*)g, (lptr_t)(void*)l, 16, 0, 0);
}

#define QSCALE 0.18033688f  // 0.125 * log2(e): folds 1/sqrt(64) and exp->exp2
#define EPS 136             // epilogue LDS row stride (u16)

// ---------- fp32 -> bf16 convert (inputs) ----------
__global__ __launch_bounds__(256) void cvt_f32_bf16(const float* __restrict__ in,
                                                    u16* __restrict__ out, int n4) {
  int i = blockIdx.x * 256 + threadIdx.x;
  if (i >= n4) return;
  float4 v = reinterpret_cast<const float4*>(in)[i];
  ushort4 o;
  o.x = f2bf(v.x); o.y = f2bf(v.y); o.z = f2bf(v.z); o.w = f2bf(v.w);
  reinterpret_cast<ushort4*>(out)[i] = o;
}

// ---------- all 4 weights fp32 -> bf16 in one dispatch ----------
__global__ __launch_bounds__(256) void cvt_w4(const float* __restrict__ Wq,
                                              const float* __restrict__ Wk,
                                              const float* __restrict__ Wv,
                                              const float* __restrict__ Wo,
                                              u16* __restrict__ out) {
  int sel = blockIdx.y;
  const float* in = sel == 0 ? Wq : sel == 1 ? Wk : sel == 2 ? Wv : Wo;
  u16* o = out + sel * 589824;
  int i = blockIdx.x * 256 + threadIdx.x;  // < 147456
  float4 v = reinterpret_cast<const float4*>(in)[i];
  ushort4 ov;
  ov.x = f2bf(v.x); ov.y = f2bf(v.y); ov.z = f2bf(v.z); ov.w = f2bf(v.w);
  reinterpret_cast<ushort4*>(o)[i] = ov;
}

// ---------- adj bit-pack:  [8,1024,1024] int32 -> [8,1024,32] u32 ----------
__global__ __launch_bounds__(256) void pack_adj(const int* __restrict__ adj,
                                                unsigned* __restrict__ bits) {
  unsigned idx = blockIdx.x * 256u + threadIdx.x;   // < 8388608
  int a = adj[idx];
  unsigned long long m = __ballot(a != 0);
  int l = threadIdx.x & 63;
  if ((l & 31) == 0) bits[idx >> 5] = (unsigned)(m >> (l & 32));
}

// ======== GEMM common: 128x128 tile, BK=32, paired-row XOR-swizzled LDS ========
// LDS tile: 64 super-rows x 128B. Super-row sr holds logical rows {2sr,2sr+1}:
// logical granule g (0..7: row=2sr+(g>>2), col16B=g&3) lives at physical slot
// pg = g ^ (sr&7).  Reads: 16 lanes (16 rows, same col) hit each bank-group
// exactly 2x -> conflict-free (m136: 2-way free).  Staged via gload_lds16 with
// the inverse permutation applied to the GLOBAL source address (m173 pattern).

// ---------- fused QKV GEMM: A[8192,768] x {Wq,Wk,Wv}[768,768]^T + bias ----------
__global__ __launch_bounds__(256, 4) void gemm_qkv(
    const u16* __restrict__ A,
    const u16* __restrict__ Wq, const u16* __restrict__ Wk, const u16* __restrict__ Wv,
    const float* __restrict__ bq, const float* __restrict__ bk, const float* __restrict__ bv,
    u16* __restrict__ Qo, u16* __restrict__ Ko, u16* __restrict__ Vo) {
  __shared__ u16 lds[2][2][128 * 32];   // 32 KB; reused by epilogue
  const int tid = threadIdx.x;
  const int w = tid >> 6, l = tid & 63;
  const int bm = blockIdx.x;
  const int bn = blockIdx.y;
  const int sel = bn / 6;          // 0=Q 1=K 2=V (wave-uniform)
  const int bnl = bn % 6;
  const int lr = l & 15, lg = l >> 4;
  const int wm = w >> 1, wn = w & 1;

  const u16* W = sel == 0 ? Wq : sel == 1 ? Wk : Wv;
  const float* bias = sel == 0 ? bq : sel == 1 ? bk : bv;

  const u16* Abase = A + (bm * 128) * 768;
  const u16* Wbase = W + (bnl * 128) * 768;

  // staging chunk geometry (2 chunks/thread, shared by A and B tiles)
  const int c0 = tid, c1 = tid + 256;
  const int sr0 = c0 >> 3, pg0 = c0 & 7, g0 = pg0 ^ (sr0 & 7);
  const int off0 = (2 * sr0 + (g0 >> 2)) * 768 + (g0 & 3) * 8;
  const int sr1 = c1 >> 3, pg1 = c1 & 7, g1 = pg1 ^ (sr1 & 7);
  const int off1 = (2 * sr1 + (g1 >> 2)) * 768 + (g1 & 3) * 8;

  // swizzled read offsets (loop-invariant)
  int aoff[4], boff[4];
#pragma unroll
  for (int i = 0; i < 4; ++i) {
    int R = wm * 64 + i * 16 + lr, sr = R >> 1;
    int g = (R & 1) * 4 + lg, pg = g ^ (sr & 7);
    aoff[i] = sr * 64 + pg * 8;
    R = wn * 64 + i * 16 + lr; sr = R >> 1;
    g = (R & 1) * 4 + lg; pg = g ^ (sr & 7);
    boff[i] = sr * 64 + pg * 8;
  }

  f32x4 acc[4][4];
#pragma unroll
  for (int i = 0; i < 4; ++i)
#pragma unroll
    for (int j = 0; j < 4; ++j) acc[i][j] = f32x4{0.f, 0.f, 0.f, 0.f};

  auto stage = [&](int buf, int k0) {
    gload_lds16(Abase + off0 + k0, &lds[buf][0][c0 * 8]);
    gload_lds16(Abase + off1 + k0, &lds[buf][0][c1 * 8]);
    gload_lds16(Wbase + off0 + k0, &lds[buf][1][c0 * 8]);
    gload_lds16(Wbase + off1 + k0, &lds[buf][1][c1 * 8]);
  };

  stage(0, 0);
  int cur = 0;
  for (int kt = 0; kt < 24; ++kt) {
    __syncthreads();
    if (kt < 23) stage(cur ^ 1, (kt + 1) * 32);
    const u16* la = &lds[cur][0][0];
    const u16* lb = &lds[cur][1][0];
    bf16x8 af[4], bw[4];
#pragma unroll
    for (int i = 0; i < 4; ++i) af[i] = *(const bf16x8*)&la[aoff[i]];
#pragma unroll
    for (int j = 0; j < 4; ++j) bw[j] = *(const bf16x8*)&lb[boff[j]];
#pragma unroll
    for (int i = 0; i < 4; ++i)
#pragma unroll
      for (int j = 0; j < 4; ++j)
        acc[i][j] = __builtin_amdgcn_mfma_f32_16x16x32_bf16(af[i], bw[j], acc[i][j], 0, 0, 0);
    cur ^= 1;
  }

  __syncthreads();                       // safe to reuse LDS as epilogue tile
  u16* ep = &lds[0][0][0];
  const int n0 = bnl * 128 + wn * 64;

  if (sel != 2) {
    const float sc = sel == 0 ? QSCALE : 1.0f;
    u16* dst = sel == 0 ? Qo : Ko;
#pragma unroll
    for (int p = 0; p < 2; ++p) {
      if (wm == p) {
#pragma unroll
        for (int j = 0; j < 4; ++j) {
          float bs = bias[n0 + j * 16 + lr];
#pragma unroll
          for (int i = 0; i < 4; ++i)
#pragma unroll
            for (int r = 0; r < 4; ++r)
              ep[(i * 16 + lg * 4 + r) * EPS + wn * 64 + j * 16 + lr] =
                  f2bf((acc[i][j][r] + bs) * sc);
        }
      }
      __syncthreads();
#pragma unroll
      for (int it = 0; it < 4; ++it) {
        int u = it * 256 + tid, row = u >> 4, cc = u & 15;
        uint4 val = *(const uint4*)&ep[row * EPS + cc * 8];
        int m = bm * 128 + p * 64 + row;
        int b_ = m >> 10, s_ = m & 1023;
        int h_ = (bnl * 128 + cc * 8) >> 6, d_ = (cc & 7) * 8;
        *(uint4*)&dst[((b_ * 12 + h_) * 1024 + s_) * 64 + d_] = val;
      }
      __syncthreads();
    }
  } else {
#pragma unroll
    for (int p = 0; p < 2; ++p) {
      if (wn == p) {
#pragma unroll
        for (int j = 0; j < 4; ++j) {
          float bs = bias[n0 + j * 16 + lr];
#pragma unroll
          for (int i = 0; i < 4; ++i) {
            ushort4 o4;
            o4.x = f2bf(acc[i][j][0] + bs);
            o4.y = f2bf(acc[i][j][1] + bs);
            o4.z = f2bf(acc[i][j][2] + bs);
            o4.w = f2bf(acc[i][j][3] + bs);
            *(ushort4*)&ep[(j * 16 + lr) * EPS + wm * 64 + i * 16 + lg * 4] = o4;
          }
        }
      }
      __syncthreads();
#pragma unroll
      for (int it = 0; it < 4; ++it) {
        int u = it * 256 + tid, row = u >> 4, cc = u & 15;
        uint4 val = *(const uint4*)&ep[row * EPS + cc * 8];
        int dg = bnl * 128 + p * 64 + row;
        int h_ = dg >> 6, d_ = dg & 63;
        int b_ = bm >> 3, s_ = (bm & 7) * 128 + cc * 8;
        *(uint4*)&Vo[((b_ * 12 + h_) * 64 + d_) * 1024 + s_] = val;
      }
      __syncthreads();
    }
  }
}

// ---------- O-proj GEMM: bf16 out[m][768] = acc + bias (resid folded into LN) ----------
__global__ __launch_bounds__(256, 4) void gemm_o(
    const u16* __restrict__ A, const u16* __restrict__ W,
    const float* __restrict__ bias, u16* __restrict__ xb) {
  __shared__ u16 lds[2][2][128 * 32];
  const int tid = threadIdx.x;
  const int w = tid >> 6, l = tid & 63;
  const int bm = blockIdx.x, bn = blockIdx.y;
  const int lr = l & 15, lg = l >> 4;
  const int wm = w >> 1, wn = w & 1;

  const u16* Abase = A + (bm * 128) * 768;
  const u16* Wbase = W + (bn * 128) * 768;

  const int c0 = tid, c1 = tid + 256;
  const int sr0 = c0 >> 3, pg0 = c0 & 7, g0 = pg0 ^ (sr0 & 7);
  const int off0 = (2 * sr0 + (g0 >> 2)) * 768 + (g0 & 3) * 8;
  const int sr1 = c1 >> 3, pg1 = c1 & 7, g1 = pg1 ^ (sr1 & 7);
  const int off1 = (2 * sr1 + (g1 >> 2)) * 768 + (g1 & 3) * 8;

  int aoff[4], boff[4];
#pragma unroll
  for (int i = 0; i < 4; ++i) {
    int R = wm * 64 + i * 16 + lr, sr = R >> 1;
    int g = (R & 1) * 4 + lg, pg = g ^ (sr & 7);
    aoff[i] = sr * 64 + pg * 8;
    R = wn * 64 + i * 16 + lr; sr = R >> 1;
    g = (R & 1) * 4 + lg; pg = g ^ (sr & 7);
    boff[i] = sr * 64 + pg * 8;
  }

  f32x4 acc[4][4];
#pragma unroll
  for (int i = 0; i < 4; ++i)
#pragma unroll
    for (int j = 0; j < 4; ++j) acc[i][j] = f32x4{0.f, 0.f, 0.f, 0.f};

  auto stage = [&](int buf, int k0) {
    gload_lds16(Abase + off0 + k0, &lds[buf][0][c0 * 8]);
    gload_lds16(Abase + off1 + k0, &lds[buf][0][c1 * 8]);
    gload_lds16(Wbase + off0 + k0, &lds[buf][1][c0 * 8]);
    gload_lds16(Wbase + off1 + k0, &lds[buf][1][c1 * 8]);
  };

  stage(0, 0);
  int cur = 0;
  for (int kt = 0; kt < 24; ++kt) {
    __syncthreads();
    if (kt < 23) stage(cur ^ 1, (kt + 1) * 32);
    const u16* la = &lds[cur][0][0];
    const u16* lb = &lds[cur][1][0];
    bf16x8 af[4], bw[4];
#pragma unroll
    for (int i = 0; i < 4; ++i) af[i] = *(const bf16x8*)&la[aoff[i]];
#pragma unroll
    for (int j = 0; j < 4; ++j) bw[j] = *(const bf16x8*)&lb[boff[j]];
#pragma unroll
    for (int i = 0; i < 4; ++i)
#pragma unroll
      for (int j = 0; j < 4; ++j)
        acc[i][j] = __builtin_amdgcn_mfma_f32_16x16x32_bf16(af[i], bw[j], acc[i][j], 0, 0, 0);
    cur ^= 1;
  }

  __syncthreads();
  u16* ep = &lds[0][0][0];
  const int n0 = bn * 128 + wn * 64;
#pragma unroll
  for (int p = 0; p < 2; ++p) {
    if (wm == p) {
#pragma unroll
      for (int j = 0; j < 4; ++j) {
        float bs = bias[n0 + j * 16 + lr];
#pragma unroll
        for (int i = 0; i < 4; ++i)
#pragma unroll
          for (int r = 0; r < 4; ++r)
            ep[(i * 16 + lg * 4 + r) * EPS + wn * 64 + j * 16 + lr] =
                f2bf(acc[i][j][r] + bs);
      }
    }
    __syncthreads();
#pragma unroll
    for (int it = 0; it < 4; ++it) {
      int u = it * 256 + tid, row = u >> 4, cc = u & 15;
      uint4 val = *(const uint4*)&ep[row * EPS + cc * 8];
      int m = bm * 128 + p * 64 + row;
      *(uint4*)&xb[m * 768 + bn * 128 + cc * 8] = val;
    }
    __syncthreads();
  }
}

// ---------- attention (round-6 proven structure + native casts + setprio) ----------
// grid (96,16): bh = blockIdx.x -> XCD = bh%8 (per-head K/V on one XCD L2).
// 4 waves cooperatively stage K-tile and V-tile [64x64] via global_load_lds
// (granule-XOR pre-swizzled global source; LDS dest linear), double-buffered,
// one __syncthreads per k-tile.  No-max softmax: p = exp2(S); ones-MFMA row-sum.
__global__ __launch_bounds__(256) void attn(
    const u16* __restrict__ Q,   // [96,1024,64]
    const u16* __restrict__ Kt,  // [96,1024,64]
    const u16* __restrict__ VT,  // [96,64,1024]
    const unsigned* __restrict__ bits, // [8,1024,32]
    u16* __restrict__ ctx) {     // [8,1024,768]
  __shared__ u16 kl[2][64 * 64];        // 16 KB
  __shared__ u16 vl[2][64 * 64];        // 16 KB
  __shared__ __bf16 plds_all[4][16 * 64]; // 8 KB
  const int tid = threadIdx.x;
  const int w = tid >> 6, l = tid & 63;
  const int lr = l & 15, lg = l >> 4;
  const int bh = blockIdx.x;               // 0..95
  const int qt = (blockIdx.y << 2) | w;    // 0..63
  const int b_ = bh / 12, h_ = bh % 12;
  __bf16* plds = plds_all[w];

  const u16* Qb = Q + (bh * 1024 + qt * 16) * 64;
  const u16* Kb = Kt + bh * 1024 * 64;
  const u16* Vb = VT + bh * 64 * 1024;
  const unsigned* wb = bits + (b_ * 1024 + qt * 16) * 32;

  bf16x8 qa0 = *(const bf16x8*)&Qb[lr * 64 + lg * 8];
  bf16x8 qa1 = *(const bf16x8*)&Qb[lr * 64 + 32 + lg * 8];

  bf16x8 vones;
#pragma unroll
  for (int i = 0; i < 8; ++i) vones[i] = (__bf16)1.0f;

  f32x4 cacc[4];
#pragma unroll
  for (int j = 0; j < 4; ++j) cacc[j] = f32x4{0.f, 0.f, 0.f, 0.f};
  f32x4 lacc = f32x4{0.f, 0.f, 0.f, 0.f};

  auto stage = [&](int buf, int k0) {
#pragma unroll
    for (int j = 0; j < 2; ++j) {
      const int seg = j * 4 + w;            // 1KB segment (wave-uniform)
      const int c = seg * 64 + l;           // chunk id
      const int row = c >> 3, g = c & 7;
      const int gp = ((g ^ (row & 7)) << 3);
      gload_lds16(Kb + (k0 + row) * 64 + gp, &kl[buf][seg * 512]);
      gload_lds16(Vb + row * 1024 + k0 + gp, &vl[buf][seg * 512]);
    }
  };

  stage(0, 0);
  __syncthreads();
  int cur = 0;

  for (int kt = 0; kt < 16; ++kt) {
    const int k0 = kt * 64;
    if (kt < 15) stage(cur ^ 1, k0 + 64);   // issue next-tile DMA first

    uint2 mm[4];
#pragma unroll
    for (int r = 0; r < 4; ++r)
      mm[r] = *(const uint2*)&wb[(lg * 4 + r) * 32 + kt * 2];

    // QK^T from LDS K-tile (swizzled, conflict-free)
    f32x4 s[4];
#pragma unroll
    for (int t = 0; t < 4; ++t) {
      const int row = t * 16 + lr;
      const int sw = row & 7;
      bf16x8 ka = *(const bf16x8*)&kl[cur][row * 64 + ((lg ^ sw) << 3)];
      bf16x8 kb2 = *(const bf16x8*)&kl[cur][row * 64 + (((4 + lg) ^ sw) << 3)];
      f32x4 z = f32x4{0.f, 0.f, 0.f, 0.f};
      z = __builtin_amdgcn_mfma_f32_16x16x32_bf16(qa0, ka, z, 0, 0, 0);
      z = __builtin_amdgcn_mfma_f32_16x16x32_bf16(qa1, kb2, z, 0, 0, 0);
      s[t] = z;
    }

    // mask + exp2 + native bf16 cast + swizzled P-LDS write
#pragma unroll
    for (int r = 0; r < 4; ++r) {
      const int q = lg * 4 + r;
      const int sw = (q & 7) << 3;
      unsigned w0 = mm[r].x >> lr;
      unsigned w1 = mm[r].y >> lr;
#pragma unroll
      for (int t = 0; t < 4; ++t) {
        unsigned bit = (t == 0) ? (w0 & 1u)
                     : (t == 1) ? ((w0 >> 16) & 1u)
                     : (t == 2) ? (w1 & 1u)
                                : ((w1 >> 16) & 1u);
        float sv = bit ? s[t][r] : -1e30f;
        plds[q * 64 + ((t * 16 + lr) ^ sw)] = (__bf16)exp2f(sv);
      }
    }
    asm volatile("s_waitcnt lgkmcnt(0)" ::: "memory");
    const int swr = (lr & 7) << 3;
    bf16x8 pa0 = *(const bf16x8*)&plds[lr * 64 + ((lg * 8) ^ swr)];
    bf16x8 pa1 = *(const bf16x8*)&plds[lr * 64 + ((32 + lg * 8) ^ swr)];

    __builtin_amdgcn_s_setprio(1);
    lacc = __builtin_amdgcn_mfma_f32_16x16x32_bf16(pa0, vones, lacc, 0, 0, 0);
    lacc = __builtin_amdgcn_mfma_f32_16x16x32_bf16(pa1, vones, lacc, 0, 0, 0);
#pragma unroll
    for (int j = 0; j < 4; ++j) {
      const int row = j * 16 + lr;
      const int sw = row & 7;
      bf16x8 v0 = *(const bf16x8*)&vl[cur][row * 64 + ((lg ^ sw) << 3)];
      bf16x8 v1 = *(const bf16x8*)&vl[cur][row * 64 + (((4 + lg) ^ sw) << 3)];
      cacc[j] = __builtin_amdgcn_mfma_f32_16x16x32_bf16(pa0, v0, cacc[j], 0, 0, 0);
      cacc[j] = __builtin_amdgcn_mfma_f32_16x16x32_bf16(pa1, v1, cacc[j], 0, 0, 0);
    }
    __builtin_amdgcn_s_setprio(0);

    __syncthreads();   // next tile resident, P reads done
    cur ^= 1;
  }

  float inv[4];
#pragma unroll
  for (int r = 0; r < 4; ++r) inv[r] = 1.0f / lacc[r];
#pragma unroll
  for (int j = 0; j < 4; ++j) {
#pragma unroll
    for (int r = 0; r < 4; ++r) {
      int q = qt * 16 + lg * 4 + r;
      ctx[(b_ * 1024 + q) * 768 + h_ * 64 + j * 16 + lr] = f2bf(cacc[j][r] * inv[r]);
    }
  }
}

// ---------- LayerNorm (+ residual add): x = bf16(gemm_o out) + fp32 inputs ----------
__global__ __launch_bounds__(256) void layernorm(const u16* __restrict__ xb,
                                                 const float* __restrict__ resid,
                                                 const float* __restrict__ gamma,
                                                 const float* __restrict__ beta,
                                                 float* __restrict__ out) {
  int row = blockIdx.x * 4 + (threadIdx.x >> 6);
  int l = threadIdx.x & 63;
  const ushort4* xr = (const ushort4*)(xb + row * 768);
  const float4* rr = (const float4*)(resid + row * 768);
  float v[12];
  float s = 0.f;
#pragma unroll
  for (int c = 0; c < 3; ++c) {
    ushort4 xs = xr[l + c * 64];
    float4 rv = rr[l + c * 64];
    v[c * 4 + 0] = bf2f(xs.x) + rv.x;
    v[c * 4 + 1] = bf2f(xs.y) + rv.y;
    v[c * 4 + 2] = bf2f(xs.z) + rv.z;
    v[c * 4 + 3] = bf2f(xs.w) + rv.w;
    s += v[c * 4 + 0] + v[c * 4 + 1] + v[c * 4 + 2] + v[c * 4 + 3];
  }
#pragma unroll
  for (int d = 1; d < 64; d <<= 1) s += __shfl_xor(s, d);
  float mu = s * (1.0f / 768.0f);
  float vs = 0.f;
#pragma unroll
  for (int k = 0; k < 12; ++k) {
    float q = v[k] - mu;
    vs += q * q;
  }
#pragma unroll
  for (int d = 1; d < 64; d <<= 1) vs += __shfl_xor(vs, d);
  float rs = rsqrtf(vs * (1.0f / 768.0f) + 1e-5f);
  const float4* g4 = (const float4*)gamma;
  const float4* b4 = (const float4*)beta;
#pragma unroll
  for (int c = 0; c < 3; ++c) {
    float4 g = g4[l + c * 64], bb = b4[l + c * 64];
    float4 o;
    o.x = (v[c * 4 + 0] - mu) * rs * g.x + bb.x;
    o.y = (v[c * 4 + 1] - mu) * rs * g.y + bb.y;
    o.z = (v[c * 4 + 2] - mu) * rs * g.z + bb.z;
    o.w = (v[c * 4 + 3] - mu) * rs * g.w + bb.w;
    ((float4*)(out + row * 768))[l + c * 64] = o;
  }
}

// ---------- launch ----------
extern "C" void kernel_launch(void* const* d_in, const int* in_sizes, int n_in,
                              void* d_out, int out_size, void* d_ws, size_t ws_size,
                              hipStream_t stream) {
  (void)in_sizes; (void)n_in; (void)out_size; (void)ws_size;
  const float* inputs = (const float*)d_in[0];
  const int* adj = (const int*)d_in[1];
  const float* Wq = (const float*)d_in[2];
  const float* bq = (const float*)d_in[3];
  const float* Wk = (const float*)d_in[4];
  const float* bk = (const float*)d_in[5];
  const float* Wv = (const float*)d_in[6];
  const float* bv = (const float*)d_in[7];
  const float* Wo = (const float*)d_in[8];
  const float* bo = (const float*)d_in[9];
  const float* gamma = (const float*)d_in[10];
  const float* beta = (const float*)d_in[11];
  float* out = (float*)d_out;
  char* ws = (char*)d_ws;

  // workspace layout (bytes)
  u16* Xbf = (u16*)(ws + 0);              // 12,582,912  (ctx bf16 aliases this later)
  u16* Wqb = (u16*)(ws + 12582912);       //  4 x 1,179,648 contiguous (cvt_w4)
  u16* Wkb = (u16*)(ws + 13762560);
  u16* Wvb = (u16*)(ws + 14942208);
  u16* Wob = (u16*)(ws + 16121856);
  u16* Qb  = (u16*)(ws + 17301504);       // 12,582,912  (xb bf16 aliases this later)
  u16* Kb  = (u16*)(ws + 29884416);       // 12,582,912
  u16* VTb = (u16*)(ws + 42467328);       // 12,582,912
  unsigned* bits = (unsigned*)(ws + 55050240); // 1,048,576  -> total 56,098,816
  u16* ctxb = (u16*)(ws + 0);
  u16* xb = (u16*)(ws + 17301504);

  cvt_f32_bf16<<<6144, 256, 0, stream>>>(inputs, Xbf, 1572864);
  cvt_w4<<<dim3(576, 4), 256, 0, stream>>>(Wq, Wk, Wv, Wo, Wqb);
  pack_adj<<<32768, 256, 0, stream>>>(adj, bits);

  gemm_qkv<<<dim3(64, 18), 256, 0, stream>>>(Xbf, Wqb, Wkb, Wvb, bq, bk, bv, Qb, Kb, VTb);

  attn<<<dim3(96, 16), 256, 0, stream>>>(Qb, Kb, VTb, bits, ctxb);

  gemm_o<<<dim3(64, 6), 256, 0, stream>>>(ctxb, Wob, bo, xb);

  layernorm<<<2048, 256, 0, stream>>>(xb, inputs, gamma, beta, out);
}

// Round 11
// 245.194 us; speedup vs baseline: 1.3047x; 1.0404x over previous
//
#include <hip/hip_runtime.h>

typedef __bf16 bf16_t;
typedef __bf16 bf16x8 __attribute__((ext_vector_type(8)));
typedef float f32x4 __attribute__((ext_vector_type(4)));
typedef unsigned short u16;

// ---------- helpers ----------
__device__ __forceinline__ u16 f2bf(float f) {
  unsigned u = __float_as_uint(f);
  unsigned r = (u + 0x7fffu + ((u >> 16) & 1u)) >> 16;
  return (u16)r;
}
__device__ __forceinline__ float bf2f(u16 u) {
  return __uint_as_float(((unsigned)u) << 16);
}
__device__ __forceinline__ unsigned pk2(float a, float b) {
  // packed bf16x2 from two floats; compiler fuses to v_cvt_pk (m240)
  unsigned lo = __builtin_bit_cast(unsigned short, (__bf16)a);
  unsigned hi = __builtin_bit_cast(unsigned short, (__bf16)b);
  return lo | (hi << 16);
}

typedef const unsigned __attribute__((address_space(1)))* gptr_t;
typedef unsigned __attribute__((address_space(3)))* lptr_t;

__device__ __forceinline__ void gload_lds16(const u16* g, u16* l) {
  __builtin_amdgcn_global_load_lds((gptr_t)(const void*)g, (lptr_t)(void*)l, 16, 0, 0);
}

#define QSCALE 0.18033688f  // 0.125 * log2(e): folds 1/sqrt(64) and exp->exp2
#define EPS 136             // epilogue LDS row stride (u16)

// ---------- merged prep: input cvt (blocks 0..6143), 4x weight cvt
// (6144..8447), adj bit-pack (8448..41215) ----------
__global__ __launch_bounds__(256) void prep(
    const float* __restrict__ inputs, const float* __restrict__ Wq,
    const float* __restrict__ Wk, const float* __restrict__ Wv,
    const float* __restrict__ Wo, const int* __restrict__ adj,
    u16* __restrict__ Xbf, u16* __restrict__ Wall, unsigned* __restrict__ bits) {
  const int bid = blockIdx.x;
  const int tid = threadIdx.x;
  if (bid < 6144) {
    int i = bid * 256 + tid;
    float4 v = reinterpret_cast<const float4*>(inputs)[i];
    ushort4 o;
    o.x = f2bf(v.x); o.y = f2bf(v.y); o.z = f2bf(v.z); o.w = f2bf(v.w);
    reinterpret_cast<ushort4*>(Xbf)[i] = o;
  } else if (bid < 8448) {
    int b2 = bid - 6144;
    int sel = b2 / 576;
    const float* in = sel == 0 ? Wq : sel == 1 ? Wk : sel == 2 ? Wv : Wo;
    int i = (b2 % 576) * 256 + tid;
    float4 v = reinterpret_cast<const float4*>(in)[i];
    ushort4 o;
    o.x = f2bf(v.x); o.y = f2bf(v.y); o.z = f2bf(v.z); o.w = f2bf(v.w);
    reinterpret_cast<ushort4*>(Wall + sel * 589824)[i] = o;
  } else {
    unsigned idx = (bid - 8448) * 256u + tid;   // < 8388608
    int a = adj[idx];
    unsigned long long m = __ballot(a != 0);
    int l = tid & 63;
    if ((l & 31) == 0) bits[idx >> 5] = (unsigned)(m >> (l & 32));
  }
}

// ======== GEMM common: 128x128 tile, BK=32, paired-row XOR-swizzled LDS ========

// ---------- fused QKV GEMM ----------
__global__ __launch_bounds__(256, 4) void gemm_qkv(
    const u16* __restrict__ A,
    const u16* __restrict__ Wq, const u16* __restrict__ Wk, const u16* __restrict__ Wv,
    const float* __restrict__ bq, const float* __restrict__ bk, const float* __restrict__ bv,
    u16* __restrict__ Qo, u16* __restrict__ Ko, u16* __restrict__ Vo) {
  __shared__ u16 lds[2][2][128 * 32];
  const int tid = threadIdx.x;
  const int w = tid >> 6, l = tid & 63;
  const int bm = blockIdx.x;
  const int bn = blockIdx.y;
  const int sel = bn / 6;
  const int bnl = bn % 6;
  const int lr = l & 15, lg = l >> 4;
  const int wm = w >> 1, wn = w & 1;

  const u16* W = sel == 0 ? Wq : sel == 1 ? Wk : Wv;
  const float* bias = sel == 0 ? bq : sel == 1 ? bk : bv;

  const u16* Abase = A + (bm * 128) * 768;
  const u16* Wbase = W + (bnl * 128) * 768;

  const int c0 = tid, c1 = tid + 256;
  const int sr0 = c0 >> 3, pg0 = c0 & 7, g0 = pg0 ^ (sr0 & 7);
  const int off0 = (2 * sr0 + (g0 >> 2)) * 768 + (g0 & 3) * 8;
  const int sr1 = c1 >> 3, pg1 = c1 & 7, g1 = pg1 ^ (sr1 & 7);
  const int off1 = (2 * sr1 + (g1 >> 2)) * 768 + (g1 & 3) * 8;

  int aoff[4], boff[4];
#pragma unroll
  for (int i = 0; i < 4; ++i) {
    int R = wm * 64 + i * 16 + lr, sr = R >> 1;
    int g = (R & 1) * 4 + lg, pg = g ^ (sr & 7);
    aoff[i] = sr * 64 + pg * 8;
    R = wn * 64 + i * 16 + lr; sr = R >> 1;
    g = (R & 1) * 4 + lg; pg = g ^ (sr & 7);
    boff[i] = sr * 64 + pg * 8;
  }

  f32x4 acc[4][4];
#pragma unroll
  for (int i = 0; i < 4; ++i)
#pragma unroll
    for (int j = 0; j < 4; ++j) acc[i][j] = f32x4{0.f, 0.f, 0.f, 0.f};

  auto stage = [&](int buf, int k0) {
    gload_lds16(Abase + off0 + k0, &lds[buf][0][c0 * 8]);
    gload_lds16(Abase + off1 + k0, &lds[buf][0][c1 * 8]);
    gload_lds16(Wbase + off0 + k0, &lds[buf][1][c0 * 8]);
    gload_lds16(Wbase + off1 + k0, &lds[buf][1][c1 * 8]);
  };

  stage(0, 0);
  int cur = 0;
  for (int kt = 0; kt < 24; ++kt) {
    __syncthreads();
    if (kt < 23) stage(cur ^ 1, (kt + 1) * 32);
    const u16* la = &lds[cur][0][0];
    const u16* lb = &lds[cur][1][0];
    bf16x8 af[4], bw[4];
#pragma unroll
    for (int i = 0; i < 4; ++i) af[i] = *(const bf16x8*)&la[aoff[i]];
#pragma unroll
    for (int j = 0; j < 4; ++j) bw[j] = *(const bf16x8*)&lb[boff[j]];
#pragma unroll
    for (int i = 0; i < 4; ++i)
#pragma unroll
      for (int j = 0; j < 4; ++j)
        acc[i][j] = __builtin_amdgcn_mfma_f32_16x16x32_bf16(af[i], bw[j], acc[i][j], 0, 0, 0);
    cur ^= 1;
  }

  __syncthreads();
  u16* ep = &lds[0][0][0];
  const int n0 = bnl * 128 + wn * 64;

  if (sel != 2) {
    const float sc = sel == 0 ? QSCALE : 1.0f;
    u16* dst = sel == 0 ? Qo : Ko;
#pragma unroll
    for (int p = 0; p < 2; ++p) {
      if (wm == p) {
#pragma unroll
        for (int j = 0; j < 4; ++j) {
          float bs = bias[n0 + j * 16 + lr];
#pragma unroll
          for (int i = 0; i < 4; ++i)
#pragma unroll
            for (int r = 0; r < 4; ++r)
              ep[(i * 16 + lg * 4 + r) * EPS + wn * 64 + j * 16 + lr] =
                  f2bf((acc[i][j][r] + bs) * sc);
        }
      }
      __syncthreads();
#pragma unroll
      for (int it = 0; it < 4; ++it) {
        int u = it * 256 + tid, row = u >> 4, cc = u & 15;
        uint4 val = *(const uint4*)&ep[row * EPS + cc * 8];
        int m = bm * 128 + p * 64 + row;
        int b_ = m >> 10, s_ = m & 1023;
        int h_ = (bnl * 128 + cc * 8) >> 6, d_ = (cc & 7) * 8;
        *(uint4*)&dst[((b_ * 12 + h_) * 1024 + s_) * 64 + d_] = val;
      }
      __syncthreads();
    }
  } else {
#pragma unroll
    for (int p = 0; p < 2; ++p) {
      if (wn == p) {
#pragma unroll
        for (int j = 0; j < 4; ++j) {
          float bs = bias[n0 + j * 16 + lr];
#pragma unroll
          for (int i = 0; i < 4; ++i) {
            ushort4 o4;
            o4.x = f2bf(acc[i][j][0] + bs);
            o4.y = f2bf(acc[i][j][1] + bs);
            o4.z = f2bf(acc[i][j][2] + bs);
            o4.w = f2bf(acc[i][j][3] + bs);
            *(ushort4*)&ep[(j * 16 + lr) * EPS + wm * 64 + i * 16 + lg * 4] = o4;
          }
        }
      }
      __syncthreads();
#pragma unroll
      for (int it = 0; it < 4; ++it) {
        int u = it * 256 + tid, row = u >> 4, cc = u & 15;
        uint4 val = *(const uint4*)&ep[row * EPS + cc * 8];
        int dg = bnl * 128 + p * 64 + row;
        int h_ = dg >> 6, d_ = dg & 63;
        int b_ = bm >> 3, s_ = (bm & 7) * 128 + cc * 8;
        *(uint4*)&Vo[((b_ * 12 + h_) * 64 + d_) * 1024 + s_] = val;
      }
      __syncthreads();
    }
  }
}

// ---------- O-proj GEMM ----------
__global__ __launch_bounds__(256, 4) void gemm_o(
    const u16* __restrict__ A, const u16* __restrict__ W,
    const float* __restrict__ bias, u16* __restrict__ xb) {
  __shared__ u16 lds[2][2][128 * 32];
  const int tid = threadIdx.x;
  const int w = tid >> 6, l = tid & 63;
  const int bm = blockIdx.x, bn = blockIdx.y;
  const int lr = l & 15, lg = l >> 4;
  const int wm = w >> 1, wn = w & 1;

  const u16* Abase = A + (bm * 128) * 768;
  const u16* Wbase = W + (bn * 128) * 768;

  const int c0 = tid, c1 = tid + 256;
  const int sr0 = c0 >> 3, pg0 = c0 & 7, g0 = pg0 ^ (sr0 & 7);
  const int off0 = (2 * sr0 + (g0 >> 2)) * 768 + (g0 & 3) * 8;
  const int sr1 = c1 >> 3, pg1 = c1 & 7, g1 = pg1 ^ (sr1 & 7);
  const int off1 = (2 * sr1 + (g1 >> 2)) * 768 + (g1 & 3) * 8;

  int aoff[4], boff[4];
#pragma unroll
  for (int i = 0; i < 4; ++i) {
    int R = wm * 64 + i * 16 + lr, sr = R >> 1;
    int g = (R & 1) * 4 + lg, pg = g ^ (sr & 7);
    aoff[i] = sr * 64 + pg * 8;
    R = wn * 64 + i * 16 + lr; sr = R >> 1;
    g = (R & 1) * 4 + lg; pg = g ^ (sr & 7);
    boff[i] = sr * 64 + pg * 8;
  }

  f32x4 acc[4][4];
#pragma unroll
  for (int i = 0; i < 4; ++i)
#pragma unroll
    for (int j = 0; j < 4; ++j) acc[i][j] = f32x4{0.f, 0.f, 0.f, 0.f};

  auto stage = [&](int buf, int k0) {
    gload_lds16(Abase + off0 + k0, &lds[buf][0][c0 * 8]);
    gload_lds16(Abase + off1 + k0, &lds[buf][0][c1 * 8]);
    gload_lds16(Wbase + off0 + k0, &lds[buf][1][c0 * 8]);
    gload_lds16(Wbase + off1 + k0, &lds[buf][1][c1 * 8]);
  };

  stage(0, 0);
  int cur = 0;
  for (int kt = 0; kt < 24; ++kt) {
    __syncthreads();
    if (kt < 23) stage(cur ^ 1, (kt + 1) * 32);
    const u16* la = &lds[cur][0][0];
    const u16* lb = &lds[cur][1][0];
    bf16x8 af[4], bw[4];
#pragma unroll
    for (int i = 0; i < 4; ++i) af[i] = *(const bf16x8*)&la[aoff[i]];
#pragma unroll
    for (int j = 0; j < 4; ++j) bw[j] = *(const bf16x8*)&lb[boff[j]];
#pragma unroll
    for (int i = 0; i < 4; ++i)
#pragma unroll
      for (int j = 0; j < 4; ++j)
        acc[i][j] = __builtin_amdgcn_mfma_f32_16x16x32_bf16(af[i], bw[j], acc[i][j], 0, 0, 0);
    cur ^= 1;
  }

  __syncthreads();
  u16* ep = &lds[0][0][0];
  const int n0 = bn * 128 + wn * 64;
#pragma unroll
  for (int p = 0; p < 2; ++p) {
    if (wm == p) {
#pragma unroll
      for (int j = 0; j < 4; ++j) {
        float bs = bias[n0 + j * 16 + lr];
#pragma unroll
        for (int i = 0; i < 4; ++i)
#pragma unroll
          for (int r = 0; r < 4; ++r)
            ep[(i * 16 + lg * 4 + r) * EPS + wn * 64 + j * 16 + lr] =
                f2bf(acc[i][j][r] + bs);
      }
    }
    __syncthreads();
#pragma unroll
    for (int it = 0; it < 4; ++it) {
      int u = it * 256 + tid, row = u >> 4, cc = u & 15;
      uint4 val = *(const uint4*)&ep[row * EPS + cc * 8];
      int m = bm * 128 + p * 64 + row;
      *(uint4*)&xb[m * 768 + bn * 128 + cc * 8] = val;
    }
    __syncthreads();
  }
}

// ---------- attention v6: swapped QK^T, packed b64 P-writes, hoisted offsets ----------
// Swapped mfma(K,Q) puts S[q=lr][k=16t+4lg+r] in each lane: the 4 per-tile
// scores are k-adjacent pairs -> P written as 4x ds_write_b64 (was 16x b16).
// P-LDS: [16][32] u32 per wave; phys = (k/2) ^ ((q&7)<<2) bank swizzle;
// reads land ascending-k b128 (verified roundtrip in analysis).
__global__ __launch_bounds__(256) void attn(
    const u16* __restrict__ Q,   // [96,1024,64]
    const u16* __restrict__ Kt,  // [96,1024,64]
    const u16* __restrict__ VT,  // [96,64,1024]
    const unsigned* __restrict__ bits, // [8,1024,32]
    u16* __restrict__ ctx) {     // [8,1024,768]
  __shared__ u16 kl[2][64 * 64];        // 16 KB
  __shared__ u16 vl[2][64 * 64];        // 16 KB
  __shared__ unsigned plds_all[4][16 * 32]; // 8 KB
  const int tid = threadIdx.x;
  const int w = tid >> 6, l = tid & 63;
  const int lr = l & 15, lg = l >> 4;
  const int bh = blockIdx.x;               // 0..95
  const int qt = (blockIdx.y << 2) | w;    // 0..63
  const int b_ = bh / 12, h_ = bh % 12;
  unsigned* plds = plds_all[w];

  const u16* Qb = Q + (bh * 1024 + qt * 16) * 64;
  const u16* Kb = Kt + bh * 1024 * 64;
  const u16* Vb = VT + bh * 64 * 1024;
  const unsigned* wbq = bits + (b_ * 1024 + qt * 16) * 32 + lr * 32; // row q=lr

  bf16x8 qa0 = *(const bf16x8*)&Qb[lr * 64 + lg * 8];
  bf16x8 qa1 = *(const bf16x8*)&Qb[lr * 64 + 32 + lg * 8];

  bf16x8 vones;
#pragma unroll
  for (int i = 0; i < 8; ++i) vones[i] = (__bf16)1.0f;

  // hoisted loop-invariant LDS offsets
  const int sw2 = (lr & 7) << 2;
  int off[4][2];                          // kl/vl rows x*16+lr (same formula)
#pragma unroll
  for (int t = 0; t < 4; ++t) {
    const int row = t * 16 + lr, sw = row & 7;
    off[t][0] = row * 64 + ((lg ^ sw) << 3);
    off[t][1] = row * 64 + (((4 + lg) ^ sw) << 3);
  }
  int pw[4];                              // P-write b64 slots (u32 index, even)
#pragma unroll
  for (int t = 0; t < 4; ++t) pw[t] = lr * 32 + ((t * 8 + 2 * lg) ^ sw2);
  const int pr0 = lr * 32 + ((lg * 4) ^ sw2);
  const int pr1 = lr * 32 + ((16 + lg * 4) ^ sw2);
  const int sh = lg * 4;

  f32x4 cacc[4];
#pragma unroll
  for (int j = 0; j < 4; ++j) cacc[j] = f32x4{0.f, 0.f, 0.f, 0.f};
  f32x4 lacc = f32x4{0.f, 0.f, 0.f, 0.f};

  auto stage = [&](int buf, int k0) {
#pragma unroll
    for (int j = 0; j < 2; ++j) {
      const int seg = j * 4 + w;            // 1KB segment (wave-uniform)
      const int c = seg * 64 + l;
      const int row = c >> 3, g = c & 7;
      const int gp = ((g ^ (row & 7)) << 3);
      gload_lds16(Kb + (k0 + row) * 64 + gp, &kl[buf][seg * 512]);
      gload_lds16(Vb + row * 1024 + k0 + gp, &vl[buf][seg * 512]);
    }
  };

  stage(0, 0);
  __syncthreads();
  int cur = 0;

  for (int kt = 0; kt < 16; ++kt) {
    if (kt < 15) stage(cur ^ 1, (kt + 1) * 64);   // next-tile DMA first

    uint2 mmq = *(const uint2*)&wbq[kt * 2];
    unsigned u0 = mmq.x >> sh;
    unsigned u1 = mmq.y >> sh;

    // swapped QK^T: s[t][r] = S[q=lr][k=t*16+4*lg+r]
    f32x4 s[4];
#pragma unroll
    for (int t = 0; t < 4; ++t) {
      bf16x8 ka = *(const bf16x8*)&kl[cur][off[t][0]];
      bf16x8 kb2 = *(const bf16x8*)&kl[cur][off[t][1]];
      f32x4 z = f32x4{0.f, 0.f, 0.f, 0.f};
      z = __builtin_amdgcn_mfma_f32_16x16x32_bf16(ka, qa0, z, 0, 0, 0);
      z = __builtin_amdgcn_mfma_f32_16x16x32_bf16(kb2, qa1, z, 0, 0, 0);
      s[t] = z;
    }

    // mask + exp2 + packed pair writes (4x b64)
#pragma unroll
    for (int t = 0; t < 4; ++t) {
      const unsigned uw = (t < 2) ? u0 : u1;
      const int bsh = (t & 1) * 16;
      float p0 = ((uw >> (bsh + 0)) & 1u) ? __builtin_amdgcn_exp2f(s[t][0]) : 0.f;
      float p1 = ((uw >> (bsh + 1)) & 1u) ? __builtin_amdgcn_exp2f(s[t][1]) : 0.f;
      float p2 = ((uw >> (bsh + 2)) & 1u) ? __builtin_amdgcn_exp2f(s[t][2]) : 0.f;
      float p3 = ((uw >> (bsh + 3)) & 1u) ? __builtin_amdgcn_exp2f(s[t][3]) : 0.f;
      uint2 pkd;
      pkd.x = pk2(p0, p1);
      pkd.y = pk2(p2, p3);
      *(uint2*)&plds[pw[t]] = pkd;
    }
    asm volatile("s_waitcnt lgkmcnt(0)" ::: "memory");
    bf16x8 pa0 = *(const bf16x8*)&plds[pr0];
    bf16x8 pa1 = *(const bf16x8*)&plds[pr1];

    __builtin_amdgcn_s_setprio(1);
    lacc = __builtin_amdgcn_mfma_f32_16x16x32_bf16(pa0, vones, lacc, 0, 0, 0);
    lacc = __builtin_amdgcn_mfma_f32_16x16x32_bf16(pa1, vones, lacc, 0, 0, 0);
#pragma unroll
    for (int j = 0; j < 4; ++j) {
      bf16x8 v0 = *(const bf16x8*)&vl[cur][off[j][0]];
      bf16x8 v1 = *(const bf16x8*)&vl[cur][off[j][1]];
      cacc[j] = __builtin_amdgcn_mfma_f32_16x16x32_bf16(pa0, v0, cacc[j], 0, 0, 0);
      cacc[j] = __builtin_amdgcn_mfma_f32_16x16x32_bf16(pa1, v1, cacc[j], 0, 0, 0);
    }
    __builtin_amdgcn_s_setprio(0);

    __syncthreads();   // next tile resident, P reads done
    cur ^= 1;
  }

  float inv[4];
#pragma unroll
  for (int r = 0; r < 4; ++r) inv[r] = 1.0f / lacc[r];
#pragma unroll
  for (int j = 0; j < 4; ++j) {
#pragma unroll
    for (int r = 0; r < 4; ++r) {
      int q = qt * 16 + lg * 4 + r;
      ctx[(b_ * 1024 + q) * 768 + h_ * 64 + j * 16 + lr] = f2bf(cacc[j][r] * inv[r]);
    }
  }
}

// ---------- LayerNorm (+ residual add) ----------
__global__ __launch_bounds__(256) void layernorm(const u16* __restrict__ xb,
                                                 const float* __restrict__ resid,
                                                 const float* __restrict__ gamma,
                                                 const float* __restrict__ beta,
                                                 float* __restrict__ out) {
  int row = blockIdx.x * 4 + (threadIdx.x >> 6);
  int l = threadIdx.x & 63;
  const ushort4* xr = (const ushort4*)(xb + row * 768);
  const float4* rr = (const float4*)(resid + row * 768);
  float v[12];
  float s = 0.f;
#pragma unroll
  for (int c = 0; c < 3; ++c) {
    ushort4 xs = xr[l + c * 64];
    float4 rv = rr[l + c * 64];
    v[c * 4 + 0] = bf2f(xs.x) + rv.x;
    v[c * 4 + 1] = bf2f(xs.y) + rv.y;
    v[c * 4 + 2] = bf2f(xs.z) + rv.z;
    v[c * 4 + 3] = bf2f(xs.w) + rv.w;
    s += v[c * 4 + 0] + v[c * 4 + 1] + v[c * 4 + 2] + v[c * 4 + 3];
  }
#pragma unroll
  for (int d = 1; d < 64; d <<= 1) s += __shfl_xor(s, d);
  float mu = s * (1.0f / 768.0f);
  float vs = 0.f;
#pragma unroll
  for (int k = 0; k < 12; ++k) {
    float q = v[k] - mu;
    vs += q * q;
  }
#pragma unroll
  for (int d = 1; d < 64; d <<= 1) vs += __shfl_xor(vs, d);
  float rs = rsqrtf(vs * (1.0f / 768.0f) + 1e-5f);
  const float4* g4 = (const float4*)gamma;
  const float4* b4 = (const float4*)beta;
#pragma unroll
  for (int c = 0; c < 3; ++c) {
    float4 g = g4[l + c * 64], bb = b4[l + c * 64];
    float4 o;
    o.x = (v[c * 4 + 0] - mu) * rs * g.x + bb.x;
    o.y = (v[c * 4 + 1] - mu) * rs * g.y + bb.y;
    o.z = (v[c * 4 + 2] - mu) * rs * g.z + bb.z;
    o.w = (v[c * 4 + 3] - mu) * rs * g.w + bb.w;
    ((float4*)(out + row * 768))[l + c * 64] = o;
  }
}

// ---------- launch ----------
extern "C" void kernel_launch(void* const* d_in, const int* in_sizes, int n_in,
                              void* d_out, int out_size, void* d_ws, size_t ws_size,
                              hipStream_t stream) {
  (void)in_sizes; (void)n_in; (void)out_size; (void)ws_size;
  const float* inputs = (const float*)d_in[0];
  const int* adj = (const int*)d_in[1];
  const float* Wq = (const float*)d_in[2];
  const float* bq = (const float*)d_in[3];
  const float* Wk = (const float*)d_in[4];
  const float* bk = (const float*)d_in[5];
  const float* Wv = (const float*)d_in[6];
  const float* bv = (const float*)d_in[7];
  const float* Wo = (const float*)d_in[8];
  const float* bo = (const float*)d_in[9];
  const float* gamma = (const float*)d_in[10];
  const float* beta = (const float*)d_in[11];
  float* out = (float*)d_out;
  char* ws = (char*)d_ws;

  // workspace layout (bytes)
  u16* Xbf = (u16*)(ws + 0);              // 12,582,912  (ctx bf16 aliases this later)
  u16* Wqb = (u16*)(ws + 12582912);       //  4 x 1,179,648 contiguous
  u16* Wkb = (u16*)(ws + 13762560);
  u16* Wvb = (u16*)(ws + 14942208);
  u16* Wob = (u16*)(ws + 16121856);
  u16* Qb  = (u16*)(ws + 17301504);       // 12,582,912  (xb bf16 aliases this later)
  u16* Kb  = (u16*)(ws + 29884416);       // 12,582,912
  u16* VTb = (u16*)(ws + 42467328);       // 12,582,912
  unsigned* bits = (unsigned*)(ws + 55050240); // 1,048,576  -> total 56,098,816
  u16* ctxb = (u16*)(ws + 0);
  u16* xb = (u16*)(ws + 17301504);

  prep<<<41216, 256, 0, stream>>>(inputs, Wq, Wk, Wv, Wo, adj, Xbf, Wqb, bits);

  gemm_qkv<<<dim3(64, 18), 256, 0, stream>>>(Xbf, Wqb, Wkb, Wvb, bq, bk, bv, Qb, Kb, VTb);

  attn<<<dim3(96, 16), 256, 0, stream>>>(Qb, Kb, VTb, bits, ctxb);

  gemm_o<<<dim3(64, 6), 256, 0, stream>>>(ctxb, Wob, bo, xb);

  layernorm<<<2048, 256, 0, stream>>>(xb, inputs, gamma, beta, out);
}